// Round 1
// 306.671 us; speedup vs baseline: 1.0405x; 1.0405x over previous
//
#include <hip/hip_runtime.h>
#include <hip/hip_bf16.h>

// ---------- types ----------
typedef __bf16 bf16x8 __attribute__((ext_vector_type(8)));
typedef float  f32x4  __attribute__((ext_vector_type(4)));

#define GLOAD_LDS16(gptr, lptr)                                                  \
  __builtin_amdgcn_global_load_lds(                                              \
      (const __attribute__((address_space(1))) void*)(gptr),                     \
      (__attribute__((address_space(3))) void*)(lptr), 16, 0, 0)

__device__ __forceinline__ unsigned short f2bf(float f) {
  __hip_bfloat16 h = __float2bfloat16(f);
  return __builtin_bit_cast(unsigned short, h);
}

// ---------- fake-quant: lane owns 4 CONSECUTIVE floats; the 128-elem block is
// the 32-lane half-wave (wave base is 64-aligned, so lanes [0,32) and [32,64)
// are each exactly one quant block). amax via 5-step butterfly (exact — fmax is
// associative), then identical clamp/scale/HW-cvt math as before:
// amax=clip(max|x|,1e-12), scale=448/amax, q=RNE_fp8(clip(x*scale,+-448)),
// deq=q*(amax/448) [mul vs ref's divide: <=1ulp, margin is 4.5x].
__device__ __forceinline__ void fq4(float* __restrict__ v) {
  float am = fmaxf(fmaxf(fabsf(v[0]), fabsf(v[1])),
                   fmaxf(fabsf(v[2]), fabsf(v[3])));
  am = fmaxf(am, __shfl_xor(am, 1));
  am = fmaxf(am, __shfl_xor(am, 2));
  am = fmaxf(am, __shfl_xor(am, 4));
  am = fmaxf(am, __shfl_xor(am, 8));
  am = fmaxf(am, __shfl_xor(am, 16));   // stays within each 32-lane half
  am = fmaxf(am, 1e-12f);
  const float scale = 448.0f / am;
  const float inv   = am * (1.0f / 448.0f);
  float c0 = fminf(fmaxf(v[0] * scale, -448.0f), 448.0f);
  float c1 = fminf(fmaxf(v[1] * scale, -448.0f), 448.0f);
  float c2 = fminf(fmaxf(v[2] * scale, -448.0f), 448.0f);
  float c3 = fminf(fmaxf(v[3] * scale, -448.0f), 448.0f);
  int pk = __builtin_amdgcn_cvt_pk_fp8_f32(c0, c1, 0, false);
  pk = __builtin_amdgcn_cvt_pk_fp8_f32(c2, c3, pk, true);
  v[0] = __builtin_amdgcn_cvt_f32_fp8(pk, 0) * inv;
  v[1] = __builtin_amdgcn_cvt_f32_fp8(pk, 1) * inv;
  v[2] = __builtin_amdgcn_cvt_f32_fp8(pk, 2) * inv;
  v[3] = __builtin_amdgcn_cvt_f32_fp8(pk, 3) * inv;
}

// ---------- activation quant: fully coalesced (16 B/lane load, 8 B/lane store)
__global__ __launch_bounds__(256) void quant_x_k(const float* __restrict__ x,
                                                 unsigned short* __restrict__ xq) {
  const size_t u = (size_t)blockIdx.x * 256 + threadIdx.x;
  float v[4];
  *(float4*)v = ((const float4*)x)[u];
  fq4(v);
  union { uint2 q; unsigned short s[4]; } pk;
#pragma unroll
  for (int e = 0; e < 4; ++e) pk.s[e] = f2bf(v[e]);
  ((uint2*)xq)[u] = pk.q;
}

// ---------- weight dual-quant: hi + fp8(residual), same coalesced mapping ----
__global__ __launch_bounds__(256) void quant_w_k(const float* __restrict__ w,
                                                 unsigned short* __restrict__ wq) {
  const size_t u = (size_t)blockIdx.x * 256 + threadIdx.x;
  float a[4], h[4], r[4];
  *(float4*)a = ((const float4*)w)[u];
#pragma unroll
  for (int i = 0; i < 4; ++i) h[i] = a[i];
  fq4(h);
#pragma unroll
  for (int i = 0; i < 4; ++i) r[i] = a[i] - h[i];
  fq4(r);
  union { uint2 q; unsigned short s[4]; } pk;
#pragma unroll
  for (int e = 0; e < 4; ++e) pk.s[e] = f2bf(h[e] + r[e]);
  ((uint2*)wq)[u] = pk.q;
}

// ---------- GEMM: C[M,N] = A[M,K] * B[N,K]^T + bias, bf16 in fp32 out ----
// (unchanged this round) Double-buffered LDS (2x32KB), ONE barrier per K-iter.
// 16B chunks XOR-swizzled within each row: measured 0 bank conflicts.
// XCD swizzle: 8 bn-blocks sharing an A-tile run consecutively on one XCD's L2.
#define BM 128
#define BN 128
#define BK 64

__global__ __launch_bounds__(256) void gemm_bt_bias(
    const unsigned short* __restrict__ A,   // bf16 bits [M,K]
    const unsigned short* __restrict__ B,   // bf16 bits [N,K]
    const float* __restrict__ bias,         // [N]
    float* __restrict__ C,                  // [M,N]
    int M, int N, int K) {
  __shared__ unsigned short ldsA[2 * BM * BK];  // 32 KB
  __shared__ unsigned short ldsB[2 * BN * BK];  // 32 KB

  const int tid  = threadIdx.x;
  const int wave = tid >> 6;
  const int lane = tid & 63;
  const int nbn  = N / BN;
  const int nbm  = M / BM;

  int bm, bn;
  if ((nbm & 7) == 0) {
    const int xcd = blockIdx.x & 7;
    const int j   = blockIdx.x >> 3;
    bn = j % nbn;
    bm = xcd * (nbm >> 3) + j / nbn;
  } else {
    bn = blockIdx.x % nbn;
    bm = blockIdx.x / nbn;
  }

  const int wr = wave >> 1;   // 0..1 (M dir)
  const int wc = wave & 1;    // 0..1 (N dir)

  f32x4 acc[4][4] = {};

  // staging: wave covers tile rows [wave*32, wave*32+32), 4 chunks of 8 rows.
  // lane i -> row (lane>>3); source col-group = (lane&7)^(lane>>3)  [swizzle]
  const int rload = wave * 32 + (lane >> 3);
  const int cload = (((lane & 7) ^ (lane >> 3)) * 8);
  const unsigned short* gA = A + (size_t)(bm * BM + rload) * K + cload;
  const unsigned short* gB = B + (size_t)(bn * BN + rload) * K + cload;
  unsigned short* lA = ldsA + wave * 2048 + lane * 8;
  unsigned short* lB = ldsB + wave * 2048 + lane * 8;

  auto stage = [&](int it, int buf) {
    const unsigned short* pA = gA + (size_t)it * BK;
    const unsigned short* pB = gB + (size_t)it * BK;
    unsigned short* dA = lA + buf * (BM * BK);
    unsigned short* dB = lB + buf * (BN * BK);
#pragma unroll
    for (int t = 0; t < 4; ++t) {
      GLOAD_LDS16(pA + (size_t)(t * 8) * K, dA + t * 512);
      GLOAD_LDS16(pB + (size_t)(t * 8) * K, dB + t * 512);
    }
  };

  auto compute = [&](const unsigned short* bA, const unsigned short* bB) {
    const int fRow = lane & 15;
    const int sw   = fRow & 7;
#pragma unroll
    for (int kc = 0; kc < 2; ++kc) {
      const int c    = kc * 4 + (lane >> 4);   // col-group 0..7
      const int sOff = ((c ^ sw) * 8);
      bf16x8 af[4], bfr[4];
#pragma unroll
      for (int i = 0; i < 4; ++i)
        af[i] = *(const bf16x8*)&bA[(wr * 64 + i * 16 + fRow) * BK + sOff];
#pragma unroll
      for (int j = 0; j < 4; ++j)
        bfr[j] = *(const bf16x8*)&bB[(wc * 64 + j * 16 + fRow) * BK + sOff];
#pragma unroll
      for (int i = 0; i < 4; ++i)
#pragma unroll
        for (int j = 0; j < 4; ++j)
          acc[i][j] = __builtin_amdgcn_mfma_f32_16x16x32_bf16(af[i], bfr[j],
                                                              acc[i][j], 0, 0, 0);
    }
  };

  stage(0, 0);
  const int niter = K / BK;   // 16 (even; required by the 2x unroll below)
  for (int it = 0; it < niter; it += 2) {
    __syncthreads();                       // drains buf0 loads; readers of buf1 done
    if (it + 1 < niter) stage(it + 1, 1);  // prefetch next tile into buf1
    compute(ldsA, ldsB);
    __syncthreads();                       // drains buf1 loads; readers of buf0 done
    if (it + 2 < niter) stage(it + 2, 0);  // prefetch into buf0
    compute(ldsA + BM * BK, ldsB + BN * BK);
  }

  // epilogue: C/D map col=lane&15, row=(lane>>4)*4+reg  [m89/m91 verified]
  const int    n0 = bn * BN + wc * 64 + (lane & 15);
  const size_t m0 = (size_t)bm * BM + wr * 64 + ((lane >> 4) << 2);
#pragma unroll
  for (int j = 0; j < 4; ++j) {
    const int col = n0 + j * 16;
    const float bv = bias[col];
#pragma unroll
    for (int i = 0; i < 4; ++i) {
      const size_t base = (m0 + (size_t)i * 16) * N + col;
#pragma unroll
      for (int r = 0; r < 4; ++r)
        C[base + (size_t)r * N] = acc[i][j][r] + bv;
    }
  }
}

// ---------- launch ----------
extern "C" void kernel_launch(void* const* d_in, const int* in_sizes, int n_in,
                              void* d_out, int out_size, void* d_ws, size_t ws_size,
                              hipStream_t stream) {
  const float* x    = (const float*)d_in[0];
  const float* w    = (const float*)d_in[1];
  const float* bias = (const float*)d_in[2];

  const int DOUT = in_sizes[2];            // 1024
  const int DIN  = in_sizes[1] / DOUT;     // 1024
  const int M    = in_sizes[0] / DIN;      // 32768

  unsigned short* xq = (unsigned short*)d_ws;                  // M*K bf16 = 64 MB
  unsigned short* wq = xq + (size_t)M * DIN;                   // N*K bf16 =  2 MB

  // 4 consecutive floats per thread -> M*DIN/4 threads, fully coalesced
  hipLaunchKernelGGL(quant_x_k, dim3((size_t)M * DIN / 4 / 256), dim3(256), 0,
                     stream, x, xq);
  hipLaunchKernelGGL(quant_w_k, dim3((size_t)DOUT * DIN / 4 / 256), dim3(256), 0,
                     stream, w, wq);

  const int grid = (M / BM) * (DOUT / BN);
  hipLaunchKernelGGL(gemm_bt_bias, dim3(grid), dim3(256), 0, stream,
                     xq, wq, bias, (float*)d_out, M, DOUT, DIN);
}